// Round 9
// baseline (2048.282 us; speedup 1.0000x reference)
//
#include <hip/hip_runtime.h>

// ---------------------------------------------------------------------------
// MTSLTM (time-aware LSTM), B=64 T=512 D=256 H=512 — round 9: tagged exchange.
// Persistent kernel: 64 blocks x 512 threads (8 waves), 1 block/CU.
// Grid: 4 batch-groups (16 batches) x 16 col-slices (32 h-cols = 128 g-cols).
//
// Exchange protocol (flag-free, drain-free):
//   Per col: one u32 word = (h_bf16 << 16) | c_bf16 | (epoch << 14).
//   h,c = tanh outputs in [-1,1] -> bf16 bit14 is ALWAYS 0 -> bit14 of the
//   c half is a free epoch tag, epoch = (t>>1)&1 (alternates per rewrite of
//   each parity buffer). Consumers poll the data words (sc1 dwordx4) until
//   all tags match the expected epoch -- the poll IS the data load; producers
//   just store (sc1) and move on. No flags, no vmcnt drains, no fences.
//   Cross-call staleness (incl. 0xAA poison, which aliases epoch 0) is killed
//   by hipMemsetAsync(hc, 0xFF) each launch (tag=1, rejected at t=1).
// ---------------------------------------------------------------------------

constexpr int kB = 64, kT = 512, kD = 256, kH = 512, kG = 2048;
constexpr int NBLK = 64, NTHR = 512;

typedef __attribute__((ext_vector_type(8))) short short8v;   // 8 bf16
typedef __attribute__((ext_vector_type(4))) float f32x4;
typedef __attribute__((ext_vector_type(4))) unsigned int uint4v;

__device__ __forceinline__ float fsig(float x)  { return 1.0f / (1.0f + __expf(-x)); }
__device__ __forceinline__ float ftanh(float x) { return 2.0f / (1.0f + __expf(-2.0f * x)) - 1.0f; }
__device__ __forceinline__ unsigned short f2bf(float f) {    // RNE f32->bf16
  unsigned u = __float_as_uint(f);
  return (unsigned short)((u + 0x7FFFu + ((u >> 16) & 1u)) >> 16);
}
__device__ __forceinline__ unsigned pk2(float a, float b) {
  return (unsigned)f2bf(a) | ((unsigned)f2bf(b) << 16);
}

__global__ __launch_bounds__(NTHR, 2) void mtsltm_kernel(
    const float* __restrict__ inp, const float* __restrict__ tdel,
    const float* __restrict__ Wd,  const float* __restrict__ W,
    const float* __restrict__ U,   const float* __restrict__ bias,
    float* __restrict__ out, unsigned* __restrict__ hc)
{
  // 56 KB LDS. h/c/x XOR-swizzled in 16B units (unit' = unit ^ (row&7)).
  __shared__ __align__(16) unsigned short h_lds[16][512];  // 16 KB
  __shared__ __align__(16) unsigned short c_lds[16][512];  // 16 KB
  __shared__ __align__(16) unsigned short x_lds[16][256];  // 8 KB
  __shared__ float g5[8][320];   // gate tiles, stride-5 (conflict-free)
  __shared__ float s5[8][320];   // Wd partials, stride-5

  const int tid = threadIdx.x, bid = blockIdx.x;
  const int bg = bid & 3;          // batch group (16-block exchange group)
  const int cs = bid >> 2;         // col slice [0,16)
  const int wv = tid >> 6, ln = tid & 63;
  const int lm = ln & 15, lg = ln >> 4;   // MFMA lane decomposition

  // ---------------- one-time: weights -> VGPRs (bf16 B-fragments) -----------
  const int gcol = (wv >> 1) * kH + cs * 32 + (wv & 1) * 16 + lm;
  short8v bU[16];                                   // U[512][gcol]
  #pragma unroll
  for (int kt = 0; kt < 16; ++kt) {
    short8v v;
    #pragma unroll
    for (int e = 0; e < 8; ++e)
      v[e] = (short)f2bf(U[(size_t)(kt * 32 + lg * 8 + e) * kG + gcol]);
    bU[kt] = v;
  }
  short8v bX[8];                                    // W[256][gcol]
  #pragma unroll
  for (int kt = 0; kt < 8; ++kt) {
    short8v v;
    #pragma unroll
    for (int e = 0; e < 8; ++e)
      v[e] = (short)f2bf(W[(size_t)(kt * 32 + lg * 8 + e) * kG + gcol]);
    bX[kt] = v;
  }
  const int kq = wv >> 1, ns = wv & 1;   // Wd: k-quarter kq, n-tile ns
  short8v bWd[4];
  #pragma unroll
  for (int kt = 0; kt < 4; ++kt) {
    short8v v;
    #pragma unroll
    for (int e = 0; e < 8; ++e)
      v[e] = (short)f2bf(Wd[(size_t)(kq * 128 + kt * 32 + lg * 8 + e) * kH
                            + cs * 32 + ns * 16 + lm]);
    bWd[kt] = v;
  }
  const float bias_r = bias[gcol];

  // ---------------- identities ----------------
  const int r = tid & 15, ch = tid >> 4, rs = r & 7;   // x staging
  const int bgl_r = bg * 16 + r;
  const int row2 = ln >> 2, q = ln & 3;                // hc staging (per wave)
  const int cm = tid >> 5, cj = tid & 31;              // cell: batch cm, col cj
  const int idxr = (cj & 15) + 16 * (wv >> 1);         // D-frag lane index
  const int jr = cm & 3, chf = cj >> 4;
  const size_t bglc = (size_t)bg * 16 + cm;
  const int colg = cs * 32 + cj;
  float c_keep = 0.0f;                                 // exact f32 cell carry
  const size_t HID = (size_t)kB * kT * kH;

  auto xgemm = [&]() -> f32x4 {    // x-part of next step's gates (+bias)
    f32x4 a = {bias_r, bias_r, bias_r, bias_r};
    #pragma unroll
    for (int kt = 0; kt < 8; ++kt) {
      short8v av = *(const short8v*)&x_lds[lm][((kt * 4 + lg) ^ (lm & 7)) * 8];
      a = __builtin_amdgcn_mfma_f32_16x16x32_bf16(av, bX[kt], a, 0, 0, 0);
    }
    return a;
  };

  // ---------------- prologue ----------------
  {  // stage x[0]
    const float* xs = inp + ((size_t)bgl_r * kT + 0) * kD + ch * 8;
    float4 a = *(const float4*)xs, b = *(const float4*)(xs + 4);
    uint4v xv;
    xv.x = pk2(a.x, a.y); xv.y = pk2(a.z, a.w);
    xv.z = pk2(b.x, b.y); xv.w = pk2(b.z, b.w);
    *(uint4v*)&x_lds[r][(ch ^ rs) * 8] = xv;
  }
  float4 xa, xb;
  {  // prefetch x[1]
    const float* xs = inp + ((size_t)bgl_r * kT + 1) * kD + ch * 8;
    xa = *(const float4*)xs; xb = *(const float4*)(xs + 4);
  }
  float tdv = tdel[bglc * kT + 0];
  __syncthreads();
  f32x4 xacc = xgemm();
  __syncthreads();   // protect x_lds before t=0's stage phase

  for (int t = 0; t < kT; ++t) {
    // ---------------- phase 1: poll-load tagged hc words + stage ------------
    if (t > 0) {
      const unsigned eptag = (unsigned)(((t - 1) >> 1) & 1) << 14;
      // lane covers cols [64wv+16q, 64wv+16q+16) of its row (16 u32 = 64B)
      const unsigned* src = hc + ((size_t)((t - 1) & 1) * kB + bg * 16 + row2) * kH
                               + 64 * wv + 16 * q;
      uint4v w0, w1, w2, w3;
      int spins = 0;
      for (;;) {
        asm volatile(
          "global_load_dwordx4 %0, %4, off sc1\n\t"
          "global_load_dwordx4 %1, %4, off offset:16 sc1\n\t"
          "global_load_dwordx4 %2, %4, off offset:32 sc1\n\t"
          "global_load_dwordx4 %3, %4, off offset:48 sc1\n\t"
          "s_waitcnt vmcnt(0)"
          : "=&v"(w0), "=&v"(w1), "=&v"(w2), "=&v"(w3)
          : "v"(src) : "memory");
        unsigned bad = (w0.x ^ eptag) | (w0.y ^ eptag) | (w0.z ^ eptag) | (w0.w ^ eptag);
        bad |= (w1.x ^ eptag) | (w1.y ^ eptag) | (w1.z ^ eptag) | (w1.w ^ eptag);
        bad |= (w2.x ^ eptag) | (w2.y ^ eptag) | (w2.z ^ eptag) | (w2.w ^ eptag);
        bad |= (w3.x ^ eptag) | (w3.y ^ eptag) | (w3.z ^ eptag) | (w3.w ^ eptag);
        if (__all((bad & 0x4000u) == 0u)) break;
        if (++spins > (1 << 18)) break;   // safety valve: fail loud, not hung
      }
      // unpack: word = (h<<16) | c(tagged bit14). h bit14 naturally 0.
      uint4v hA, hB, cA, cB;
      hA.x = (w0.x >> 16) | (w0.y & 0xFFFF0000u);
      hA.y = (w0.z >> 16) | (w0.w & 0xFFFF0000u);
      hA.z = (w1.x >> 16) | (w1.y & 0xFFFF0000u);
      hA.w = (w1.z >> 16) | (w1.w & 0xFFFF0000u);
      hB.x = (w2.x >> 16) | (w2.y & 0xFFFF0000u);
      hB.y = (w2.z >> 16) | (w2.w & 0xFFFF0000u);
      hB.z = (w3.x >> 16) | (w3.y & 0xFFFF0000u);
      hB.w = (w3.z >> 16) | (w3.w & 0xFFFF0000u);
      cA.x = (w0.x & 0xBFFFu) | ((w0.y & 0xBFFFu) << 16);
      cA.y = (w0.z & 0xBFFFu) | ((w0.w & 0xBFFFu) << 16);
      cA.z = (w1.x & 0xBFFFu) | ((w1.y & 0xBFFFu) << 16);
      cA.w = (w1.z & 0xBFFFu) | ((w1.w & 0xBFFFu) << 16);
      cB.x = (w2.x & 0xBFFFu) | ((w2.y & 0xBFFFu) << 16);
      cB.y = (w2.z & 0xBFFFu) | ((w2.w & 0xBFFFu) << 16);
      cB.z = (w3.x & 0xBFFFu) | ((w3.y & 0xBFFFu) << 16);
      cB.w = (w3.z & 0xBFFFu) | ((w3.w & 0xBFFFu) << 16);
      const int rsw = row2 & 7;
      const int u0 = ((8 * wv + 2 * q)     ^ rsw) * 8;
      const int u1 = ((8 * wv + 2 * q + 1) ^ rsw) * 8;
      *(uint4v*)&h_lds[row2][u0] = hA;
      *(uint4v*)&h_lds[row2][u1] = hB;
      *(uint4v*)&c_lds[row2][u0] = cA;
      *(uint4v*)&c_lds[row2][u1] = cB;
    }
    if (t + 1 < kT) {   // stage x[t+1] from prefetched regs
      uint4v xv;
      xv.x = pk2(xa.x, xa.y); xv.y = pk2(xa.z, xa.w);
      xv.z = pk2(xb.x, xb.y); xv.w = pk2(xb.z, xb.w);
      *(uint4v*)&x_lds[r][(ch ^ rs) * 8] = xv;
    }
    __syncthreads();                                   // barrier A

    // ---------------- phase 2: h@U (C-in=xacc) + c@Wd + xgemm(t+1) ----------
    if (t > 0) {
      f32x4 a0 = xacc, a1 = {0.f, 0.f, 0.f, 0.f};
      #pragma unroll
      for (int kt = 0; kt < 8; ++kt) {
        short8v av = *(const short8v*)&h_lds[lm][((kt * 4 + lg) ^ (lm & 7)) * 8];
        a0 = __builtin_amdgcn_mfma_f32_16x16x32_bf16(av, bU[kt], a0, 0, 0, 0);
      }
      #pragma unroll
      for (int kt = 8; kt < 16; ++kt) {
        short8v av = *(const short8v*)&h_lds[lm][((kt * 4 + lg) ^ (lm & 7)) * 8];
        a1 = __builtin_amdgcn_mfma_f32_16x16x32_bf16(av, bU[kt], a1, 0, 0, 0);
      }
      f32x4 aw = {0.f, 0.f, 0.f, 0.f};
      #pragma unroll
      for (int kt = 0; kt < 4; ++kt) {
        short8v av = *(const short8v*)&c_lds[lm][((kq * 16 + kt * 4 + lg) ^ (lm & 7)) * 8];
        aw = __builtin_amdgcn_mfma_f32_16x16x32_bf16(av, bWd[kt], aw, 0, 0, 0);
      }
      #pragma unroll
      for (int j = 0; j < 4; ++j) {
        g5[wv][ln * 5 + j] = a0[j] + a1[j];
        s5[wv][ln * 5 + j] = aw[j];
      }
    } else {
      #pragma unroll
      for (int j = 0; j < 4; ++j) g5[wv][ln * 5 + j] = xacc[j];
    }
    if (t + 1 < kT) xacc = xgemm();   // pre-B (x_lds hazard window)
    __syncthreads();                                   // barrier B

    // ---------------- phase 3: cell + tagged store (no drain, no flag) ------
    float hout, tcn;
    {
      float g0 = g5[0 + chf][idxr * 5 + jr];
      float g1 = g5[2 + chf][idxr * 5 + jr];
      float g2 = g5[4 + chf][idxr * 5 + jr];
      float g3 = g5[6 + chf][idxr * 5 + jr];
      float sw = 0.f;
      if (t > 0) {
        #pragma unroll
        for (int q2 = 0; q2 < 4; ++q2) sw += s5[2 * q2 + chf][idxr * 5 + jr];
      }
      float csv  = ftanh(sw);
      float cadj = (c_keep - csv) + csv / __logf(2.71828182845904523536f + tdv);
      float gi = fsig(g0), gf = fsig(g1), gg = ftanh(g2), go = fsig(g3);
      float cnew = fmaf(gf, cadj, gi * gg);
      tcn  = ftanh(cnew);                  // = c_out
      hout = ftanh(go * tcn);              // = tanh(o * tanh(c_new))
      c_keep = tcn;
      // tagged exchange word: h in high half, c (bit14 := epoch) in low half
      unsigned wout = ((unsigned)f2bf(hout) << 16) | (unsigned)f2bf(tcn)
                    | ((unsigned)((t >> 1) & 1) << 14);
      __hip_atomic_store(hc + ((size_t)(t & 1) * kB + bglc) * kH + colg, wout,
                         __ATOMIC_RELAXED, __HIP_MEMORY_SCOPE_AGENT);
    }

    // ---------------- shadow work (off the critical path) -------------------
    __builtin_nontemporal_store(hout, &out[(bglc * kT + t) * kH + colg]);
    if (t == kT - 1) {
      out[HID + bglc * kH + colg] = hout;                      // h_t
      out[HID + (size_t)kB * kH + bglc * kH + colg] = tcn;     // c_t
    }
    if (t + 2 < kT) {
      const float* xs = inp + ((size_t)bgl_r * kT + (t + 2)) * kD + ch * 8;
      xa = *(const float4*)xs; xb = *(const float4*)(xs + 4);
    }
    if (t + 1 < kT) tdv = tdel[bglc * kT + (t + 1)];
  }
}

extern "C" void kernel_launch(void* const* d_in, const int* in_sizes, int n_in,
                              void* d_out, int out_size, void* d_ws, size_t ws_size,
                              hipStream_t stream)
{
  const float* inp  = (const float*)d_in[0];
  const float* td   = (const float*)d_in[1];
  const float* Wd   = (const float*)d_in[2];
  const float* W    = (const float*)d_in[3];
  const float* U    = (const float*)d_in[4];
  const float* bias = (const float*)d_in[5];
  float* out = (float*)d_out;

  // ws: hc[2][64][512] u32 (256 KB). Memset 0xFF each launch: tag bit14 = 1
  // -> rejected at t=1 (expects epoch 0); also defeats the 0xAA poison
  // (whose bit14 = 0 would alias epoch 0).
  unsigned* hc = (unsigned*)d_ws;
  (void)hipMemsetAsync(hc, 0xFF, (size_t)2 * kB * kH * sizeof(unsigned), stream);
  mtsltm_kernel<<<dim3(NBLK), dim3(NTHR), 0, stream>>>(inp, td, Wd, W, U, bias,
                                                       out, hc);
}

// Round 11
// 1771.567 us; speedup vs baseline: 1.1562x; 1.1562x over previous
//
#include <hip/hip_runtime.h>

// ---------------------------------------------------------------------------
// MTSLTM (time-aware LSTM), B=64 T=512 D=256 H=512 — round 11.
// Persistent kernel: 64 blocks x 512 threads (8 waves), 1 block/CU.
// Grid: 4 batch-groups (16 batches, bg=bid&3) x 16 col-slices (32 h-cols).
// Exchange: agent-scope sc1 ONLY (r10 proved sc0/XCD-L2 exchange is unsafe).
//
// vs r7 (1821us base):
//  * packed hc word per col: (h_bf16<<16)|c_bf16, epoch tag ((t>>1)&1)<<14 in
//    the c half (tanh outputs -> bit14 free; r9-proven). Consumer validates
//    tags after its load; retries (steady-state: never).
//  * NO producer-side vmcnt drain: all three barriers are lgkm-only
//    (s_waitcnt lgkmcnt(0); s_barrier). Flag posts right after barrier C.
//  * h/c sc1 loads issued FIRST in phase 1, xgemm (x[t]@W) runs in their
//    latency shadow; vmcnt(0)+sched_barrier(0) before use (rule-18 fence).
//  * x[t+1] staged in phase 3 (barrier C separates it from next xgemm read).
//  * stride-5 LDS layouts for gate/Wd partials (conflict-free).
// ---------------------------------------------------------------------------

constexpr int kB = 64, kT = 512, kD = 256, kH = 512, kG = 2048;
constexpr int NBLK = 64, NTHR = 512;

typedef __attribute__((ext_vector_type(8))) short short8v;   // 8 bf16
typedef __attribute__((ext_vector_type(4))) float f32x4;
typedef __attribute__((ext_vector_type(4))) unsigned int uint4v;

__device__ __forceinline__ float fsig(float x)  { return 1.0f / (1.0f + __expf(-x)); }
__device__ __forceinline__ float ftanh(float x) { return 2.0f / (1.0f + __expf(-2.0f * x)) - 1.0f; }
__device__ __forceinline__ unsigned short f2bf(float f) {    // RNE f32->bf16
  unsigned u = __float_as_uint(f);
  return (unsigned short)((u + 0x7FFFu + ((u >> 16) & 1u)) >> 16);
}

#define LGKM_BARRIER() asm volatile("s_waitcnt lgkmcnt(0)\n\ts_barrier" ::: "memory")

__global__ __launch_bounds__(NTHR, 1) void mtsltm_kernel(
    const float* __restrict__ inp, const float* __restrict__ tdel,
    const float* __restrict__ Wd,  const float* __restrict__ W,
    const float* __restrict__ U,   const float* __restrict__ bias,
    float* __restrict__ out,
    unsigned* __restrict__ hc, unsigned* __restrict__ flags)
{
  // 50.5 KB LDS. h/c/x XOR-swizzled in 16B units (unit' = unit ^ (row&7)).
  __shared__ __align__(16) unsigned short h_lds[16][512];  // 16 KB
  __shared__ __align__(16) unsigned short c_lds[16][512];  // 16 KB
  __shared__ __align__(16) unsigned short x_lds[16][256];  // 8 KB
  __shared__ float g5[8][320];   // gate tiles, stride-5 (conflict-free)
  __shared__ float s5[8][320];   // Wd partials, stride-5

  const int tid = threadIdx.x, bid = blockIdx.x;
  const int bg = bid & 3;          // batch group (16-block exchange group)
  const int cs = bid >> 2;         // col slice [0,16): h-cols cs*32..cs*32+32
  const int wv = tid >> 6, ln = tid & 63;
  const int lm = ln & 15, lg = ln >> 4;   // MFMA lane decomposition

  // ---------------- one-time: weights -> VGPRs (bf16 B-fragments) -----------
  const int gcol = (wv >> 1) * kH + cs * 32 + (wv & 1) * 16 + lm;
  short8v bU[16];                                   // U[512][gcol]
  #pragma unroll
  for (int kt = 0; kt < 16; ++kt) {
    short8v v;
    #pragma unroll
    for (int e = 0; e < 8; ++e)
      v[e] = (short)f2bf(U[(size_t)(kt * 32 + lg * 8 + e) * kG + gcol]);
    bU[kt] = v;
  }
  short8v bX[8];                                    // W[256][gcol]
  #pragma unroll
  for (int kt = 0; kt < 8; ++kt) {
    short8v v;
    #pragma unroll
    for (int e = 0; e < 8; ++e)
      v[e] = (short)f2bf(W[(size_t)(kt * 32 + lg * 8 + e) * kG + gcol]);
    bX[kt] = v;
  }
  const int kq = wv >> 1, ns = wv & 1;   // Wd: k-quarter kq, n-tile ns
  short8v bWd[4];
  #pragma unroll
  for (int kt = 0; kt < 4; ++kt) {
    short8v v;
    #pragma unroll
    for (int e = 0; e < 8; ++e)
      v[e] = (short)f2bf(Wd[(size_t)(kq * 128 + kt * 32 + lg * 8 + e) * kH
                            + cs * 32 + ns * 16 + lm]);
    bWd[kt] = v;
  }
  const float bias_r = bias[gcol];

  // ---------------- identities ----------------
  const int r = tid & 15, ch = tid >> 4, rs = r & 7;   // x staging
  const int bgl_r = bg * 16 + r;
  const int row2 = ln >> 2, q = ln & 3;                // hc staging (per wave)
  const int cm = tid >> 5, cj = tid & 31;              // cell: batch cm, col cj
  const int lidx = ((cm >> 2) << 4) | (cj & 15), jr = cm & 3, chf = cj >> 4;
  const size_t bglc = (size_t)bg * 16 + cm;
  const int colg = cs * 32 + cj;
  float c_keep = 0.0f;                                 // exact f32 cell carry
  const size_t HID = (size_t)kB * kT * kH;

  auto xgemm = [&]() -> f32x4 {    // x[t]-part of this step's gates (+bias)
    f32x4 a = {bias_r, bias_r, bias_r, bias_r};
    #pragma unroll
    for (int kt = 0; kt < 8; ++kt) {
      short8v av = *(const short8v*)&x_lds[lm][((kt * 4 + lg) ^ (lm & 7)) * 8];
      a = __builtin_amdgcn_mfma_f32_16x16x32_bf16(av, bX[kt], a, 0, 0, 0);
    }
    return a;
  };

  // ---------------- prologue: stage x[0], prefetch x[1] ---------------------
  {
    const float* xs = inp + ((size_t)bgl_r * kT + 0) * kD + ch * 8;
    float4 a = *(const float4*)xs, b = *(const float4*)(xs + 4);
    uint4v xv;
    xv.x = (unsigned)f2bf(a.x) | ((unsigned)f2bf(a.y) << 16);
    xv.y = (unsigned)f2bf(a.z) | ((unsigned)f2bf(a.w) << 16);
    xv.z = (unsigned)f2bf(b.x) | ((unsigned)f2bf(b.y) << 16);
    xv.w = (unsigned)f2bf(b.z) | ((unsigned)f2bf(b.w) << 16);
    *(uint4v*)&x_lds[r][(ch ^ rs) * 8] = xv;
  }
  float4 xa, xb;
  {
    const float* xs = inp + ((size_t)bgl_r * kT + 1) * kD + ch * 8;
    xa = *(const float4*)xs; xb = *(const float4*)(xs + 4);
  }
  float tdv = tdel[bglc * kT + 0];
  __syncthreads();

  for (int t = 0; t < kT; ++t) {
    // ============ phase 1: poll -> issue hc loads -> xgemm -> land ==========
    uint4v w0, w1, w2, w3;
    const unsigned* src = nullptr;
    if (t > 0) {
      // per-wave poll of its 2 producers' flags (slices 2wv, 2wv+1)
      const unsigned* fp = flags + (size_t)((2 * wv + (ln & 1)) * 4 + bg) * 32;
      int spins = 0;
      for (;;) {
        unsigned v = 0xFFFFFFFFu;
        if (ln < 2)
          asm volatile("global_load_dword %0, %1, off sc1\n\ts_waitcnt vmcnt(0)"
                       : "=&v"(v) : "v"(fp) : "memory");
        if (__all(v >= (unsigned)t)) break;
        if (++spins > (1 << 20)) break;   // safety valve
      }
      // issue the packed hc loads (16 cols/lane), DO NOT wait yet
      src = hc + ((size_t)((t - 1) & 1) * kB + bg * 16 + row2) * kH
               + 64 * wv + 16 * q;
      asm volatile(
        "global_load_dwordx4 %0, %4, off sc1\n\t"
        "global_load_dwordx4 %1, %4, off offset:16 sc1\n\t"
        "global_load_dwordx4 %2, %4, off offset:32 sc1\n\t"
        "global_load_dwordx4 %3, %4, off offset:48 sc1"
        : "=&v"(w0), "=&v"(w1), "=&v"(w2), "=&v"(w3)
        : "v"(src) : "memory");
    }
    // x[t]@W in the load-latency shadow (x_lds staged in phase 3 of t-1)
    f32x4 xacc = xgemm();
    if (t > 0) {
      asm volatile("s_waitcnt vmcnt(0)" ::: "memory");
      __builtin_amdgcn_sched_barrier(0);
      // epoch validation (retry ~never: stores were issued ~1400cy ago)
      const unsigned ep = ((unsigned)((t - 1) >> 1) & 1u) << 14;
      for (int vt = 0; vt < 4096; ++vt) {
        unsigned bad = (w0.x ^ ep) | (w0.y ^ ep) | (w0.z ^ ep) | (w0.w ^ ep)
                     | (w1.x ^ ep) | (w1.y ^ ep) | (w1.z ^ ep) | (w1.w ^ ep)
                     | (w2.x ^ ep) | (w2.y ^ ep) | (w2.z ^ ep) | (w2.w ^ ep)
                     | (w3.x ^ ep) | (w3.y ^ ep) | (w3.z ^ ep) | (w3.w ^ ep);
        if (__all((bad & 0x4000u) == 0u)) break;
        asm volatile(
          "global_load_dwordx4 %0, %4, off sc1\n\t"
          "global_load_dwordx4 %1, %4, off offset:16 sc1\n\t"
          "global_load_dwordx4 %2, %4, off offset:32 sc1\n\t"
          "global_load_dwordx4 %3, %4, off offset:48 sc1\n\t"
          "s_waitcnt vmcnt(0)"
          : "=&v"(w0), "=&v"(w1), "=&v"(w2), "=&v"(w3)
          : "v"(src) : "memory");
        __builtin_amdgcn_sched_barrier(0);
      }
      // unpack: word = (h<<16) | c (bit14 = epoch tag, masked off)
      uint4v hA, hB, cA, cB;
      hA.x = (w0.x >> 16) | (w0.y & 0xFFFF0000u);
      hA.y = (w0.z >> 16) | (w0.w & 0xFFFF0000u);
      hA.z = (w1.x >> 16) | (w1.y & 0xFFFF0000u);
      hA.w = (w1.z >> 16) | (w1.w & 0xFFFF0000u);
      hB.x = (w2.x >> 16) | (w2.y & 0xFFFF0000u);
      hB.y = (w2.z >> 16) | (w2.w & 0xFFFF0000u);
      hB.z = (w3.x >> 16) | (w3.y & 0xFFFF0000u);
      hB.w = (w3.z >> 16) | (w3.w & 0xFFFF0000u);
      cA.x = (w0.x & 0xBFFFu) | ((w0.y & 0xBFFFu) << 16);
      cA.y = (w0.z & 0xBFFFu) | ((w0.w & 0xBFFFu) << 16);
      cA.z = (w1.x & 0xBFFFu) | ((w1.y & 0xBFFFu) << 16);
      cA.w = (w1.z & 0xBFFFu) | ((w1.w & 0xBFFFu) << 16);
      cB.x = (w2.x & 0xBFFFu) | ((w2.y & 0xBFFFu) << 16);
      cB.y = (w2.z & 0xBFFFu) | ((w2.w & 0xBFFFu) << 16);
      cB.z = (w3.x & 0xBFFFu) | ((w3.y & 0xBFFFu) << 16);
      cB.w = (w3.z & 0xBFFFu) | ((w3.w & 0xBFFFu) << 16);
      const int rsw = row2 & 7;
      const int ub = 8 * wv + 2 * q;
      *(uint4v*)&h_lds[row2][((ub)     ^ rsw) * 8] = hA;
      *(uint4v*)&h_lds[row2][((ub + 1) ^ rsw) * 8] = hB;
      *(uint4v*)&c_lds[row2][((ub)     ^ rsw) * 8] = cA;
      *(uint4v*)&c_lds[row2][((ub + 1) ^ rsw) * 8] = cB;
    }
    LGKM_BARRIER();                                    // barrier A (no vmcnt)

    // ============ phase 2: h@U (C-in=xacc) + c@Wd ===========================
    if (t > 0) {
      f32x4 a0 = xacc, a1 = {0.f, 0.f, 0.f, 0.f};
      #pragma unroll
      for (int kt = 0; kt < 8; ++kt) {
        short8v av = *(const short8v*)&h_lds[lm][((kt * 4 + lg) ^ (lm & 7)) * 8];
        a0 = __builtin_amdgcn_mfma_f32_16x16x32_bf16(av, bU[kt], a0, 0, 0, 0);
      }
      #pragma unroll
      for (int kt = 8; kt < 16; ++kt) {
        short8v av = *(const short8v*)&h_lds[lm][((kt * 4 + lg) ^ (lm & 7)) * 8];
        a1 = __builtin_amdgcn_mfma_f32_16x16x32_bf16(av, bU[kt], a1, 0, 0, 0);
      }
      f32x4 aw = {0.f, 0.f, 0.f, 0.f};
      #pragma unroll
      for (int kt = 0; kt < 4; ++kt) {
        short8v av = *(const short8v*)&c_lds[lm][((kq * 16 + kt * 4 + lg) ^ (lm & 7)) * 8];
        aw = __builtin_amdgcn_mfma_f32_16x16x32_bf16(av, bWd[kt], aw, 0, 0, 0);
      }
      #pragma unroll
      for (int j = 0; j < 4; ++j) {
        g5[wv][ln * 5 + j] = a0[j] + a1[j];
        s5[wv][ln * 5 + j] = aw[j];
      }
    } else {
      #pragma unroll
      for (int j = 0; j < 4; ++j) g5[wv][ln * 5 + j] = xacc[j];
    }
    LGKM_BARRIER();                                    // barrier B (no vmcnt)

    // ============ phase 3: cell -> tagged hc store -> x-stage -> flag =======
    float hout, tcn;
    {
      float g0 = g5[0 + chf][lidx * 5 + jr];
      float g1 = g5[2 + chf][lidx * 5 + jr];
      float g2 = g5[4 + chf][lidx * 5 + jr];
      float g3 = g5[6 + chf][lidx * 5 + jr];
      float sw = 0.f;
      if (t > 0) {
        #pragma unroll
        for (int q2 = 0; q2 < 4; ++q2) sw += s5[2 * q2 + chf][lidx * 5 + jr];
      }
      float csv  = ftanh(sw);
      float cadj = (c_keep - csv) + csv / __logf(2.71828182845904523536f + tdv);
      float gi = fsig(g0), gf = fsig(g1), gg = ftanh(g2), go = fsig(g3);
      float cnew = fmaf(gf, cadj, gi * gg);
      tcn  = ftanh(cnew);                  // = c_out
      hout = ftanh(go * tcn);              // = tanh(o * tanh(c_new))
      c_keep = tcn;
      unsigned wout = ((unsigned)f2bf(hout) << 16) | (unsigned)f2bf(tcn)
                    | (((unsigned)(t >> 1) & 1u) << 14);
      unsigned* dst = hc + ((size_t)(t & 1) * kB + bglc) * kH + colg;
      asm volatile("global_store_dword %0, %1, off sc1"
                   :: "v"(dst), "v"(wout) : "memory");
    }
    if (t + 1 < kT) {   // stage x[t+1] (consumed by next step's phase-1 xgemm)
      uint4v xv;
      xv.x = (unsigned)f2bf(xa.x) | ((unsigned)f2bf(xa.y) << 16);
      xv.y = (unsigned)f2bf(xa.z) | ((unsigned)f2bf(xa.w) << 16);
      xv.z = (unsigned)f2bf(xb.x) | ((unsigned)f2bf(xb.y) << 16);
      xv.w = (unsigned)f2bf(xb.z) | ((unsigned)f2bf(xb.w) << 16);
      *(uint4v*)&x_lds[r][(ch ^ rs) * 8] = xv;
    }
    LGKM_BARRIER();   // barrier C: all waves' hc stores ISSUED, x_lds ready
    if (tid == 0) {
      unsigned* fdst = flags + (size_t)bid * 32;
      unsigned fv = (unsigned)(t + 1);
      asm volatile("global_store_dword %0, %1, off sc1"
                   :: "v"(fdst), "v"(fv) : "memory");
    }

    // ============ shadow work (off the critical path) =======================
    __builtin_nontemporal_store(hout, &out[(bglc * kT + t) * kH + colg]);
    if (t == kT - 1) {
      out[HID + bglc * kH + colg] = hout;                      // h_t
      out[HID + (size_t)kB * kH + bglc * kH + colg] = tcn;     // c_t
    }
    if (t + 2 < kT) {
      const float* xs = inp + ((size_t)bgl_r * kT + (t + 2)) * kD + ch * 8;
      xa = *(const float4*)xs; xb = *(const float4*)(xs + 4);
    }
    if (t + 1 < kT) tdv = tdel[bglc * kT + (t + 1)];
  }
}

extern "C" void kernel_launch(void* const* d_in, const int* in_sizes, int n_in,
                              void* d_out, int out_size, void* d_ws, size_t ws_size,
                              hipStream_t stream)
{
  const float* inp  = (const float*)d_in[0];
  const float* td   = (const float*)d_in[1];
  const float* Wd   = (const float*)d_in[2];
  const float* W    = (const float*)d_in[3];
  const float* U    = (const float*)d_in[4];
  const float* bias = (const float*)d_in[5];
  float* out = (float*)d_out;

  // ws: hc[2][64][512] u32 (256 KB) | flags 64*32 u32 (8 KB).
  // hc memset 0xFF: tag bit14 = 1 everywhere -> t=1 (expects epoch 0) rejects
  // any pre-launch garbage incl. the harness 0xAA poison. flags memset 0.
  unsigned* hc    = (unsigned*)d_ws;
  unsigned* flags = hc + (size_t)2 * kB * kH;

  (void)hipMemsetAsync(hc, 0xFF, (size_t)2 * kB * kH * sizeof(unsigned), stream);
  (void)hipMemsetAsync(flags, 0, (size_t)NBLK * 32 * sizeof(unsigned), stream);
  mtsltm_kernel<<<dim3(NBLK), dim3(NTHR), 0, stream>>>(inp, td, Wd, W, U, bias,
                                                       out, hc, flags);
}

// Round 12
// 1676.971 us; speedup vs baseline: 1.2214x; 1.0564x over previous
//
#include <hip/hip_runtime.h>

// ---------------------------------------------------------------------------
// MTSLTM (time-aware LSTM), B=64 T=512 D=256 H=512 — round 12.
// Persistent kernel: 64 blocks x 512 threads (8 waves), 1 block/CU.
// Grid: 4 batch-groups (16 batches, bg=bid&3) x 16 col-slices (32 h-cols).
// Exchange: agent-scope sc1 + epoch-tagged words (r11 protocol).
//
// vs r11 (1771us):
//  * vmcnt-poison fix: ALL slow VMEM (out[] HBM store — deferred one step in
//    a register — x[t+2] prefetch, tdel) issues in phase 2, where no vmem
//    wait exists; completes during GEMM+cell. The phase-1 vmcnt(0) no longer
//    drains HBM-latency ops (this was silently serializing every round).
//  * speculative hc load: issue data load BEFORE any flag check; validate
//    epoch tags; on miss fall back to subflag poll + bounded reload.
//  * per-wave subflags posted right after each wave's hc store (no drain,
//    no cross-wave join before the flag; tags absorb store/flag reordering).
//    Barrier C (g5/s5 lifetime) sits AFTER the flag post — off the
//    producer->consumer critical path.
//  * x_lds single-buffered: read in phase 1 (xgemm), written in phase 2,
//    barrier-separated in both directions.
// ---------------------------------------------------------------------------

constexpr int kB = 64, kT = 512, kD = 256, kH = 512, kG = 2048;
constexpr int NBLK = 64, NTHR = 512;

typedef __attribute__((ext_vector_type(8))) short short8v;   // 8 bf16
typedef __attribute__((ext_vector_type(4))) float f32x4;
typedef __attribute__((ext_vector_type(4))) unsigned int uint4v;

__device__ __forceinline__ float fsig(float x)  { return 1.0f / (1.0f + __expf(-x)); }
__device__ __forceinline__ float ftanh(float x) { return 2.0f / (1.0f + __expf(-2.0f * x)) - 1.0f; }
__device__ __forceinline__ unsigned short f2bf(float f) {    // RNE f32->bf16
  unsigned u = __float_as_uint(f);
  return (unsigned short)((u + 0x7FFFu + ((u >> 16) & 1u)) >> 16);
}

#define LGKM_BARRIER() asm volatile("s_waitcnt lgkmcnt(0)\n\ts_barrier" ::: "memory")

__global__ __launch_bounds__(NTHR, 1) void mtsltm_kernel(
    const float* __restrict__ inp, const float* __restrict__ tdel,
    const float* __restrict__ Wd,  const float* __restrict__ W,
    const float* __restrict__ U,   const float* __restrict__ bias,
    float* __restrict__ out,
    unsigned* __restrict__ hc, unsigned* __restrict__ flags)
{
  // 60.5 KB LDS. h/c/x XOR-swizzled in 16B units (unit' = unit ^ (row&7)).
  __shared__ __align__(16) unsigned short h_lds[16][512];  // 16 KB
  __shared__ __align__(16) unsigned short c_lds[16][512];  // 16 KB
  __shared__ __align__(16) unsigned short x_lds[16][256];  // 8 KB
  __shared__ float g5[8][320];   // gate tiles, stride-5 (conflict-free)
  __shared__ float s5[8][320];   // Wd partials, stride-5

  const int tid = threadIdx.x, bid = blockIdx.x;
  const int bg = bid & 3;          // batch group (16-block exchange group)
  const int cs = bid >> 2;         // col slice [0,16): h-cols cs*32..cs*32+32
  const int wv = tid >> 6, ln = tid & 63;
  const int lm = ln & 15, lg = ln >> 4;   // MFMA lane decomposition

  // ---------------- one-time: weights -> VGPRs (bf16 B-fragments) -----------
  const int gcol = (wv >> 1) * kH + cs * 32 + (wv & 1) * 16 + lm;
  short8v bU[16];                                   // U[512][gcol]
  #pragma unroll
  for (int kt = 0; kt < 16; ++kt) {
    short8v v;
    #pragma unroll
    for (int e = 0; e < 8; ++e)
      v[e] = (short)f2bf(U[(size_t)(kt * 32 + lg * 8 + e) * kG + gcol]);
    bU[kt] = v;
  }
  short8v bX[8];                                    // W[256][gcol]
  #pragma unroll
  for (int kt = 0; kt < 8; ++kt) {
    short8v v;
    #pragma unroll
    for (int e = 0; e < 8; ++e)
      v[e] = (short)f2bf(W[(size_t)(kt * 32 + lg * 8 + e) * kG + gcol]);
    bX[kt] = v;
  }
  const int kq = wv >> 1, ns = wv & 1;   // Wd: k-quarter kq, n-tile ns
  short8v bWd[4];
  #pragma unroll
  for (int kt = 0; kt < 4; ++kt) {
    short8v v;
    #pragma unroll
    for (int e = 0; e < 8; ++e)
      v[e] = (short)f2bf(Wd[(size_t)(kq * 128 + kt * 32 + lg * 8 + e) * kH
                            + cs * 32 + ns * 16 + lm]);
    bWd[kt] = v;
  }
  const float bias_r = bias[gcol];

  // ---------------- identities ----------------
  const int r = tid & 15, ch = tid >> 4, rs = r & 7;   // x staging
  const int bgl_r = bg * 16 + r;
  const int row2 = ln >> 2, q = ln & 3;                // hc staging (per wave)
  const int cm = tid >> 5, cj = tid & 31;              // cell: batch cm, col cj
  const int lidx = ((cm >> 2) << 4) | (cj & 15), jr = cm & 3, chf = cj >> 4;
  const size_t bglc = (size_t)bg * 16 + cm;
  const int colg = cs * 32 + cj;
  float c_keep = 0.0f;                                 // exact f32 cell carry
  float o_hold = 0.0f;                                 // deferred out value
  const size_t HID = (size_t)kB * kT * kH;

  auto xgemm = [&]() -> f32x4 {    // x[t]-part of this step's gates (+bias)
    f32x4 a = {bias_r, bias_r, bias_r, bias_r};
    #pragma unroll
    for (int kt = 0; kt < 8; ++kt) {
      short8v av = *(const short8v*)&x_lds[lm][((kt * 4 + lg) ^ (lm & 7)) * 8];
      a = __builtin_amdgcn_mfma_f32_16x16x32_bf16(av, bX[kt], a, 0, 0, 0);
    }
    return a;
  };

  // ---------------- prologue: stage x[0], prefetch x[1], tdel[0] ------------
  {
    const float* xs = inp + ((size_t)bgl_r * kT + 0) * kD + ch * 8;
    float4 a = *(const float4*)xs, b = *(const float4*)(xs + 4);
    uint4v xv;
    xv.x = (unsigned)f2bf(a.x) | ((unsigned)f2bf(a.y) << 16);
    xv.y = (unsigned)f2bf(a.z) | ((unsigned)f2bf(a.w) << 16);
    xv.z = (unsigned)f2bf(b.x) | ((unsigned)f2bf(b.y) << 16);
    xv.w = (unsigned)f2bf(b.z) | ((unsigned)f2bf(b.w) << 16);
    *(uint4v*)&x_lds[r][(ch ^ rs) * 8] = xv;
  }
  float4 xa, xb;
  {
    const float* xs = inp + ((size_t)bgl_r * kT + 1) * kD + ch * 8;
    xa = *(const float4*)xs; xb = *(const float4*)(xs + 4);
  }
  float tdv = tdel[bglc * kT + 0];
  __syncthreads();

  for (int t = 0; t < kT; ++t) {
    // ============ phase 1: SPEC hc load -> xgemm -> validate/fallback =======
    uint4v w0, w1, w2, w3;
    const unsigned* src = nullptr;
    if (t > 0) {
      // speculative: issue packed hc loads BEFORE any flag check
      src = hc + ((size_t)((t - 1) & 1) * kB + bg * 16 + row2) * kH
               + 64 * wv + 16 * q;
      asm volatile(
        "global_load_dwordx4 %0, %4, off sc1\n\t"
        "global_load_dwordx4 %1, %4, off offset:16 sc1\n\t"
        "global_load_dwordx4 %2, %4, off offset:32 sc1\n\t"
        "global_load_dwordx4 %3, %4, off offset:48 sc1"
        : "=&v"(w0), "=&v"(w1), "=&v"(w2), "=&v"(w3)
        : "v"(src) : "memory");
    }
    // x[t]@W in the load-latency shadow (x_lds staged in phase 2 of t-1)
    f32x4 xacc = xgemm();
    if (t > 0) {
      asm volatile("s_waitcnt vmcnt(0)" ::: "memory");
      __builtin_amdgcn_sched_barrier(0);
      const unsigned ep = (((unsigned)(t - 1) >> 1) & 1u) << 14;
      unsigned bad = (w0.x ^ ep) | (w0.y ^ ep) | (w0.z ^ ep) | (w0.w ^ ep)
                   | (w1.x ^ ep) | (w1.y ^ ep) | (w1.z ^ ep) | (w1.w ^ ep)
                   | (w2.x ^ ep) | (w2.y ^ ep) | (w2.z ^ ep) | (w2.w ^ ep)
                   | (w3.x ^ ep) | (w3.y ^ ep) | (w3.z ^ ep) | (w3.w ^ ep);
      if (!__all((bad & 0x4000u) == 0u)) {
        // fallback: poll the 16 sub-flags of producers 2wv, 2wv+1
        const unsigned* fp = flags +
            (size_t)(((((2 * wv + (ln >> 3)) << 2) | bg) * 8) + (ln & 7)) * 32;
        int spins = 0;
        for (;;) {
          unsigned v = 0xFFFFFFFFu;
          if (ln < 16)
            asm volatile("global_load_dword %0, %1, off sc1\n\ts_waitcnt vmcnt(0)"
                         : "=&v"(v) : "v"(fp) : "memory");
          if (__all(v >= (unsigned)t)) break;
          if (++spins > (1 << 20)) break;   // safety valve
        }
        for (int vt = 0; vt < 4096; ++vt) {
          asm volatile(
            "global_load_dwordx4 %0, %4, off sc1\n\t"
            "global_load_dwordx4 %1, %4, off offset:16 sc1\n\t"
            "global_load_dwordx4 %2, %4, off offset:32 sc1\n\t"
            "global_load_dwordx4 %3, %4, off offset:48 sc1\n\t"
            "s_waitcnt vmcnt(0)"
            : "=&v"(w0), "=&v"(w1), "=&v"(w2), "=&v"(w3)
            : "v"(src) : "memory");
          __builtin_amdgcn_sched_barrier(0);
          bad = (w0.x ^ ep) | (w0.y ^ ep) | (w0.z ^ ep) | (w0.w ^ ep)
              | (w1.x ^ ep) | (w1.y ^ ep) | (w1.z ^ ep) | (w1.w ^ ep)
              | (w2.x ^ ep) | (w2.y ^ ep) | (w2.z ^ ep) | (w2.w ^ ep)
              | (w3.x ^ ep) | (w3.y ^ ep) | (w3.z ^ ep) | (w3.w ^ ep);
          if (__all((bad & 0x4000u) == 0u)) break;
        }
      }
      // unpack: word = (h<<16) | c (bit14 = epoch tag, masked off)
      uint4v hA, hB, cA, cB;
      hA.x = (w0.x >> 16) | (w0.y & 0xFFFF0000u);
      hA.y = (w0.z >> 16) | (w0.w & 0xFFFF0000u);
      hA.z = (w1.x >> 16) | (w1.y & 0xFFFF0000u);
      hA.w = (w1.z >> 16) | (w1.w & 0xFFFF0000u);
      hB.x = (w2.x >> 16) | (w2.y & 0xFFFF0000u);
      hB.y = (w2.z >> 16) | (w2.w & 0xFFFF0000u);
      hB.z = (w3.x >> 16) | (w3.y & 0xFFFF0000u);
      hB.w = (w3.z >> 16) | (w3.w & 0xFFFF0000u);
      cA.x = (w0.x & 0xBFFFu) | ((w0.y & 0xBFFFu) << 16);
      cA.y = (w0.z & 0xBFFFu) | ((w0.w & 0xBFFFu) << 16);
      cA.z = (w1.x & 0xBFFFu) | ((w1.y & 0xBFFFu) << 16);
      cA.w = (w1.z & 0xBFFFu) | ((w1.w & 0xBFFFu) << 16);
      cB.x = (w2.x & 0xBFFFu) | ((w2.y & 0xBFFFu) << 16);
      cB.y = (w2.z & 0xBFFFu) | ((w2.w & 0xBFFFu) << 16);
      cB.z = (w3.x & 0xBFFFu) | ((w3.y & 0xBFFFu) << 16);
      cB.w = (w3.z & 0xBFFFu) | ((w3.w & 0xBFFFu) << 16);
      const int rsw = row2 & 7;
      const int ub = 8 * wv + 2 * q;
      *(uint4v*)&h_lds[row2][((ub)     ^ rsw) * 8] = hA;
      *(uint4v*)&h_lds[row2][((ub + 1) ^ rsw) * 8] = hB;
      *(uint4v*)&c_lds[row2][((ub)     ^ rsw) * 8] = cA;
      *(uint4v*)&c_lds[row2][((ub + 1) ^ rsw) * 8] = cB;
    }
    LGKM_BARRIER();                                    // barrier A (no vmcnt)

    // ============ phase 2: shadow VMEM issues + GEMM ========================
    // slow ops live HERE: no vmem waits until next phase 1, ~1500cy away.
    if (t > 0)
      __builtin_nontemporal_store(o_hold, &out[(bglc * kT + (t - 1)) * kH + colg]);
    if (t + 1 < kT) {   // stage x[t+1] (read by xgemm only after barrier B)
      uint4v xv;
      xv.x = (unsigned)f2bf(xa.x) | ((unsigned)f2bf(xa.y) << 16);
      xv.y = (unsigned)f2bf(xa.z) | ((unsigned)f2bf(xa.w) << 16);
      xv.z = (unsigned)f2bf(xb.x) | ((unsigned)f2bf(xb.y) << 16);
      xv.w = (unsigned)f2bf(xb.z) | ((unsigned)f2bf(xb.w) << 16);
      *(uint4v*)&x_lds[r][(ch ^ rs) * 8] = xv;
    }
    if (t + 2 < kT) {   // prefetch x[t+2] (HBM; completes during GEMM+cell)
      const float* xs = inp + ((size_t)bgl_r * kT + (t + 2)) * kD + ch * 8;
      xa = *(const float4*)xs; xb = *(const float4*)(xs + 4);
    }
    float tdn = (t + 1 < kT) ? tdel[bglc * kT + (t + 1)] : 0.0f;
    if (t > 0) {
      f32x4 a0 = xacc, a1 = {0.f, 0.f, 0.f, 0.f};
      #pragma unroll
      for (int kt = 0; kt < 8; ++kt) {
        short8v av = *(const short8v*)&h_lds[lm][((kt * 4 + lg) ^ (lm & 7)) * 8];
        a0 = __builtin_amdgcn_mfma_f32_16x16x32_bf16(av, bU[kt], a0, 0, 0, 0);
      }
      #pragma unroll
      for (int kt = 8; kt < 16; ++kt) {
        short8v av = *(const short8v*)&h_lds[lm][((kt * 4 + lg) ^ (lm & 7)) * 8];
        a1 = __builtin_amdgcn_mfma_f32_16x16x32_bf16(av, bU[kt], a1, 0, 0, 0);
      }
      f32x4 aw = {0.f, 0.f, 0.f, 0.f};
      #pragma unroll
      for (int kt = 0; kt < 4; ++kt) {
        short8v av = *(const short8v*)&c_lds[lm][((kq * 16 + kt * 4 + lg) ^ (lm & 7)) * 8];
        aw = __builtin_amdgcn_mfma_f32_16x16x32_bf16(av, bWd[kt], aw, 0, 0, 0);
      }
      #pragma unroll
      for (int j = 0; j < 4; ++j) {
        g5[wv][ln * 5 + j] = a0[j] + a1[j];
        s5[wv][ln * 5 + j] = aw[j];
      }
    } else {
      #pragma unroll
      for (int j = 0; j < 4; ++j) g5[wv][ln * 5 + j] = xacc[j];
    }
    LGKM_BARRIER();                                    // barrier B (no vmcnt)

    // ============ phase 3: cell -> tagged hc store -> per-wave subflag ======
    {
      float g0 = g5[0 + chf][lidx * 5 + jr];
      float g1 = g5[2 + chf][lidx * 5 + jr];
      float g2 = g5[4 + chf][lidx * 5 + jr];
      float g3 = g5[6 + chf][lidx * 5 + jr];
      float sw = 0.f;
      if (t > 0) {
        #pragma unroll
        for (int q2 = 0; q2 < 4; ++q2) sw += s5[2 * q2 + chf][lidx * 5 + jr];
      }
      float csv  = ftanh(sw);
      float cadj = (c_keep - csv) + csv / __logf(2.71828182845904523536f + tdv);
      float gi = fsig(g0), gf = fsig(g1), gg = ftanh(g2), go = fsig(g3);
      float cnew = fmaf(gf, cadj, gi * gg);
      float tcn  = ftanh(cnew);            // = c_out
      float hout = ftanh(go * tcn);        // = tanh(o * tanh(c_new))
      c_keep = tcn;
      o_hold = hout;
      unsigned wout = ((unsigned)f2bf(hout) << 16) | (unsigned)f2bf(tcn)
                    | (((unsigned)(t >> 1) & 1u) << 14);
      unsigned* dst = hc + ((size_t)(t & 1) * kB + bglc) * kH + colg;
      asm volatile("global_store_dword %0, %1, off sc1"
                   :: "v"(dst), "v"(wout) : "memory");
      if (ln == 0) {   // this wave's data issued -> publish its sub-flag
        unsigned* fdst = flags + (size_t)(bid * 8 + wv) * 32;
        unsigned fv = (unsigned)(t + 1);
        asm volatile("global_store_dword %0, %1, off sc1"
                     :: "v"(fdst), "v"(fv) : "memory");
      }
    }
    tdv = tdn;
    LGKM_BARRIER();   // barrier C: g5/s5 lifetime (off the inter-block path)
  }

  // ---------------- epilogue: t = kT-1 outputs ------------------------------
  out[(bglc * kT + (kT - 1)) * kH + colg] = o_hold;
  out[HID + bglc * kH + colg] = o_hold;                      // h_t
  out[HID + (size_t)kB * kH + bglc * kH + colg] = c_keep;    // c_t
}

extern "C" void kernel_launch(void* const* d_in, const int* in_sizes, int n_in,
                              void* d_out, int out_size, void* d_ws, size_t ws_size,
                              hipStream_t stream)
{
  const float* inp  = (const float*)d_in[0];
  const float* td   = (const float*)d_in[1];
  const float* Wd   = (const float*)d_in[2];
  const float* W    = (const float*)d_in[3];
  const float* U    = (const float*)d_in[4];
  const float* bias = (const float*)d_in[5];
  float* out = (float*)d_out;

  // ws: hc[2][64][512] u32 (256 KB) | subflags 64*8*32 u32 (64 KB).
  // hc memset 0xFF: tag bit14=1 everywhere -> t=1 (epoch 0) rejects stale
  // data incl. the harness 0xAA poison. flags memset 0.
  unsigned* hc    = (unsigned*)d_ws;
  unsigned* flags = hc + (size_t)2 * kB * kH;

  (void)hipMemsetAsync(hc, 0xFF, (size_t)2 * kB * kH * sizeof(unsigned), stream);
  (void)hipMemsetAsync(flags, 0, (size_t)NBLK * 8 * 32 * sizeof(unsigned), stream);
  mtsltm_kernel<<<dim3(NBLK), dim3(NTHR), 0, stream>>>(inp, td, Wd, W, U, bias,
                                                       out, hc, flags);
}